// Round 1
// baseline (674.367 us; speedup 1.0000x reference)
//
#include <hip/hip_runtime.h>
#include <cstdint>
#include <cstddef>

// AttnBlock: B=4, C=512, H=W=64 (N=4096). All-fp32 I/O, bf16 MFMA internally.
//
// Pipeline:
//  1. gn_stats:      per (b,group) mean/rstd          (128 blocks)
//  2. norm_transpose: x(B,C,N) -> Hnt bf16 (B,N,C)    (LDS transpose)
//  3. f32_to_bf16 x4: weights -> bf16
//  4. gemm_nt: Qt[b] = Hnt[b] @ Wq^T + bq   (4096x512, K=512)  [n][c] layout
//              Kt[b] = Hnt[b] @ Wk^T + bk
//              Vcn[b] = Wv @ Hnt[b]^T + bv  (512x4096)          [c][n] layout
//  5. per batch: S = Qt Kt^T * C^-0.5 (fp32, 4096x4096)
//                P = softmax_rows(S) -> bf16
//                Ot[b] = P @ Vcn[b]^T (4096x512)                 [i][c] layout
//  6. gemm_nt: out[b] = Wp @ Ot[b]^T + bp + residual (fp32, [c][n])

#define CDIM 512
#define NSP  4096
#define NB   4

using bf16x8 = __attribute__((ext_vector_type(8))) __bf16;
using f32x4  = __attribute__((ext_vector_type(4))) float;
using u16x4  = __attribute__((ext_vector_type(4))) unsigned short;

__device__ __forceinline__ unsigned short f2bf(float f) {
  unsigned int u = __float_as_uint(f);
  u += 0x7fffu + ((u >> 16) & 1u);
  return (unsigned short)(u >> 16);
}

__device__ __forceinline__ void async_copy16(const unsigned short* g, unsigned short* l) {
  __builtin_amdgcn_global_load_lds(
      (const __attribute__((address_space(1))) void*)g,
      (__attribute__((address_space(3))) void*)l, 16, 0, 0);
}

// ---------------- GroupNorm stats: one block per (b, group) ----------------
__global__ __launch_bounds__(256) void gn_stats(const float* __restrict__ x,
                                                float* __restrict__ stats) {
  const size_t base = (size_t)blockIdx.x * 65536;  // 16 ch * 4096, contiguous
  const float4* p = (const float4*)(x + base);
  float s = 0.f, ss = 0.f;
  for (int i = threadIdx.x; i < 16384; i += 256) {
    float4 v = p[i];
    s  += v.x + v.y + v.z + v.w;
    ss += v.x*v.x + v.y*v.y + v.z*v.z + v.w*v.w;
  }
  for (int off = 32; off; off >>= 1) {
    s  += __shfl_xor(s, off);
    ss += __shfl_xor(ss, off);
  }
  __shared__ float rs[4], rss[4];
  const int w = threadIdx.x >> 6;
  if ((threadIdx.x & 63) == 0) { rs[w] = s; rss[w] = ss; }
  __syncthreads();
  if (threadIdx.x == 0) {
    float S  = rs[0] + rs[1] + rs[2] + rs[3];
    float SS = rss[0] + rss[1] + rss[2] + rss[3];
    float mean = S * (1.f / 65536.f);
    float var  = SS * (1.f / 65536.f) - mean * mean;
    stats[2 * blockIdx.x]     = mean;
    stats[2 * blockIdx.x + 1] = rsqrtf(var + 1e-6f);
  }
}

// ------------- normalize + transpose: x(B,C,N) f32 -> Hnt(B,N,C) bf16 -------
__global__ __launch_bounds__(256) void norm_transpose(
    const float* __restrict__ x, const float* __restrict__ stats,
    const float* __restrict__ gns, const float* __restrict__ gnb,
    unsigned short* __restrict__ hnt) {
  __shared__ float tile[64][65];
  const int b  = blockIdx.z;
  const int c0 = blockIdx.y * 64, n0 = blockIdx.x * 64;
  const int tx = threadIdx.x & 63, ty = threadIdx.x >> 6;
  for (int i = 0; i < 16; ++i) {
    int cl = ty * 16 + i;
    int c  = c0 + cl;
    int g  = c >> 4;
    float mean = stats[(b * 32 + g) * 2];
    float rstd = stats[(b * 32 + g) * 2 + 1];
    float v = x[((size_t)(b * CDIM + c)) * NSP + n0 + tx];
    tile[cl][tx] = (v - mean) * rstd * gns[c] + gnb[c];
  }
  __syncthreads();
  for (int i = 0; i < 16; ++i) {
    int nl = ty * 16 + i;
    hnt[((size_t)(b * NSP + n0 + nl)) * CDIM + c0 + tx] = f2bf(tile[tx][nl]);
  }
}

// ---------------- fp32 -> bf16 weight conversion ----------------
__global__ __launch_bounds__(256) void f32_to_bf16(const float* __restrict__ src,
                                                   unsigned short* __restrict__ dst) {
  int i = blockIdx.x * 256 + threadIdx.x;  // grid covers exactly n/4
  float4 v = ((const float4*)src)[i];
  u16x4 o = {f2bf(v.x), f2bf(v.y), f2bf(v.z), f2bf(v.w)};
  *(u16x4*)(dst + (size_t)i * 4) = o;
}

// ---------------- NT GEMM: D[M,N] = scale * A[M,K] @ Bt[N,K]^T ----------------
// BIAS_MODE: 0 none, 1 per-row (bias[m]), 2 per-col (bias[n])
template <int BIAS_MODE, int OUT_BF16, int RESID>
__global__ __launch_bounds__(256) void gemm_nt(
    const unsigned short* __restrict__ A, const unsigned short* __restrict__ Bt,
    void* __restrict__ Dv, const float* __restrict__ bias,
    const float* __restrict__ resid, int M, int N, int K, float scale,
    long sA, long sB, long sD, long sR) {
  __shared__ unsigned short lsA[128 * 32];
  __shared__ unsigned short lsB[128 * 32];
  const int tid = threadIdx.x;
  const int w = tid >> 6, lane = tid & 63;
  const int wr = w >> 1, wc = w & 1;
  const int b = blockIdx.z;
  const int bm0 = blockIdx.y * 128, bn0 = blockIdx.x * 128;
  const unsigned short* Ab = A + (size_t)b * sA;
  const unsigned short* Bb = Bt + (size_t)b * sB;

  f32x4 acc[4][4] = {};
  const int r0  = w * 16 + (lane >> 2);  // staging row within a 64-row half
  const int kof = (lane & 3) * 8;
  const int fr  = lane & 15, kf = (lane >> 4) * 8;

  for (int k0 = 0; k0 < K; k0 += 32) {
    for (int it = 0; it < 2; ++it) {
      int row = it * 64 + r0;
      async_copy16(Ab + (size_t)(bm0 + row) * K + k0 + kof, lsA + row * 32 + kof);
      async_copy16(Bb + (size_t)(bn0 + row) * K + k0 + kof, lsB + row * 32 + kof);
    }
    __syncthreads();
    bf16x8 af[4], bff[4];
    for (int i = 0; i < 4; ++i) {
      af[i]  = *(const bf16x8*)(lsA + (wr * 64 + i * 16 + fr) * 32 + kf);
      bff[i] = *(const bf16x8*)(lsB + (wc * 64 + i * 16 + fr) * 32 + kf);
    }
    for (int i = 0; i < 4; ++i)
      for (int j = 0; j < 4; ++j)
        acc[i][j] = __builtin_amdgcn_mfma_f32_16x16x32_bf16(af[i], bff[j], acc[i][j], 0, 0, 0);
    __syncthreads();
  }

  const int col_l = lane & 15, row_l = (lane >> 4) * 4;
  for (int i = 0; i < 4; ++i)
    for (int j = 0; j < 4; ++j) {
      int gr = bm0 + wr * 64 + i * 16 + row_l;
      int gc = bn0 + wc * 64 + j * 16 + col_l;
      for (int r = 0; r < 4; ++r) {
        float v = acc[i][j][r] * scale;
        if (BIAS_MODE == 1) v += bias[gr + r];
        if (BIAS_MODE == 2) v += bias[gc];
        if (RESID) v += resid[(size_t)b * sR + (size_t)(gr + r) * N + gc];
        if (OUT_BF16)
          ((unsigned short*)Dv)[(size_t)b * sD + (size_t)(gr + r) * N + gc] = f2bf(v);
        else
          ((float*)Dv)[(size_t)b * sD + (size_t)(gr + r) * N + gc] = v;
      }
    }
}

// ---------------- row softmax: S fp32 (4096 cols) -> P bf16 ----------------
__global__ __launch_bounds__(256) void softmax_rows(const float* __restrict__ S,
                                                    unsigned short* __restrict__ P) {
  const int row = blockIdx.x;
  const float4* s = (const float4*)(S + (size_t)row * NSP);
  const int t = threadIdx.x;
  float4 v[4];
  float m = -1e30f;
  for (int i = 0; i < 4; ++i) {
    v[i] = s[i * 256 + t];
    m = fmaxf(m, fmaxf(fmaxf(v[i].x, v[i].y), fmaxf(v[i].z, v[i].w)));
  }
  for (int off = 32; off; off >>= 1) m = fmaxf(m, __shfl_xor(m, off));
  __shared__ float red[8];
  const int w = t >> 6;
  if ((t & 63) == 0) red[w] = m;
  __syncthreads();
  m = fmaxf(fmaxf(red[0], red[1]), fmaxf(red[2], red[3]));
  float sum = 0.f;
  for (int i = 0; i < 4; ++i) {
    v[i].x = __expf(v[i].x - m);
    v[i].y = __expf(v[i].y - m);
    v[i].z = __expf(v[i].z - m);
    v[i].w = __expf(v[i].w - m);
    sum += v[i].x + v[i].y + v[i].z + v[i].w;
  }
  for (int off = 32; off; off >>= 1) sum += __shfl_xor(sum, off);
  if ((t & 63) == 0) red[4 + w] = sum;
  __syncthreads();
  float inv = 1.f / (red[4] + red[5] + red[6] + red[7]);
  for (int i = 0; i < 4; ++i) {
    u16x4 o = {f2bf(v[i].x * inv), f2bf(v[i].y * inv), f2bf(v[i].z * inv), f2bf(v[i].w * inv)};
    *(u16x4*)(P + (size_t)row * NSP + (size_t)(i * 256 + t) * 4) = o;
  }
}

extern "C" void kernel_launch(void* const* d_in, const int* in_sizes, int n_in,
                              void* d_out, int out_size, void* d_ws, size_t ws_size,
                              hipStream_t stream) {
  const float* hs  = (const float*)d_in[0];
  const float* gns = (const float*)d_in[1];
  const float* gnb = (const float*)d_in[2];
  const float* wq  = (const float*)d_in[3];
  const float* bq  = (const float*)d_in[4];
  const float* wk  = (const float*)d_in[5];
  const float* bk  = (const float*)d_in[6];
  const float* wv  = (const float*)d_in[7];
  const float* bv  = (const float*)d_in[8];
  const float* wp  = (const float*)d_in[9];
  const float* bp  = (const float*)d_in[10];

  char* p = (char*)d_ws;
  unsigned short* wqb = (unsigned short*)p; p += (size_t)CDIM * CDIM * 2;
  unsigned short* wkb = (unsigned short*)p; p += (size_t)CDIM * CDIM * 2;
  unsigned short* wvb = (unsigned short*)p; p += (size_t)CDIM * CDIM * 2;
  unsigned short* wpb = (unsigned short*)p; p += (size_t)CDIM * CDIM * 2;
  const size_t bn = (size_t)NSP * CDIM;         // 2M elements per batch
  unsigned short* hnt = (unsigned short*)p; p += NB * bn * 2;
  unsigned short* qt  = (unsigned short*)p; p += NB * bn * 2;
  unsigned short* kt  = (unsigned short*)p; p += NB * bn * 2;
  unsigned short* vcn = (unsigned short*)p; p += NB * bn * 2;
  unsigned short* ot  = (unsigned short*)p; p += NB * bn * 2;
  float* S = (float*)p;          p += (size_t)NSP * NSP * 4;
  unsigned short* P = (unsigned short*)p; p += (size_t)NSP * NSP * 2;
  float* stats = (float*)p;      p += 256 * 4;

  f32_to_bf16<<<256, 256, 0, stream>>>(wq, wqb);
  f32_to_bf16<<<256, 256, 0, stream>>>(wk, wkb);
  f32_to_bf16<<<256, 256, 0, stream>>>(wv, wvb);
  f32_to_bf16<<<256, 256, 0, stream>>>(wp, wpb);
  gn_stats<<<128, 256, 0, stream>>>(hs, stats);
  norm_transpose<<<dim3(64, 8, 4), 256, 0, stream>>>(hs, stats, gns, gnb, hnt);

  const long sBN = (long)bn;
  // Qt[b] (4096x512) = Hnt[b](4096x512) @ Wq(512x512)^T + bq (per-col)
  gemm_nt<2, 1, 0><<<dim3(4, 32, NB), 256, 0, stream>>>(
      hnt, wqb, qt, bq, nullptr, NSP, CDIM, CDIM, 1.f, sBN, 0, sBN, 0);
  gemm_nt<2, 1, 0><<<dim3(4, 32, NB), 256, 0, stream>>>(
      hnt, wkb, kt, bk, nullptr, NSP, CDIM, CDIM, 1.f, sBN, 0, sBN, 0);
  // Vcn[b] (512x4096) = Wv(512x512) @ Hnt[b](4096x512)^T + bv (per-row)
  gemm_nt<1, 1, 0><<<dim3(32, 4, NB), 256, 0, stream>>>(
      wvb, hnt, vcn, bv, nullptr, CDIM, NSP, CDIM, 1.f, 0, sBN, sBN, 0);

  const float sc = 0.044194173824159216f;  // 512^-0.5
  for (int b = 0; b < NB; ++b) {
    // S (4096x4096 fp32) = Qt[b] @ Kt[b]^T * C^-0.5
    gemm_nt<0, 0, 0><<<dim3(32, 32, 1), 256, 0, stream>>>(
        qt + (size_t)b * bn, kt + (size_t)b * bn, S, nullptr, nullptr,
        NSP, NSP, CDIM, sc, 0, 0, 0, 0);
    softmax_rows<<<NSP, 256, 0, stream>>>(S, P);
    // Ot[b] (4096x512) = P(4096x4096) @ Vcn[b](512x4096)^T
    gemm_nt<0, 1, 0><<<dim3(4, 32, 1), 256, 0, stream>>>(
        P, vcn + (size_t)b * bn, ot + (size_t)b * bn, nullptr, nullptr,
        NSP, CDIM, NSP, 1.f, 0, 0, 0, 0);
  }
  // out[b] (512x4096 fp32) = Wp @ Ot[b]^T + bp (per-row) + residual
  gemm_nt<1, 0, 1><<<dim3(32, 4, NB), 256, 0, stream>>>(
      wpb, ot, (float*)d_out, bp, hs, CDIM, NSP, CDIM, 1.f, 0, sBN, sBN, sBN);
}

// Round 2
// 446.260 us; speedup vs baseline: 1.5112x; 1.5112x over previous
//
#include <hip/hip_runtime.h>
#include <cstdint>
#include <cstddef>

// AttnBlock: B=4, C=512, H=W=64 (N=4096). All-fp32 I/O, bf16 MFMA internally.
// R2: split-K PV (4 splits, partials reuse S buffer) + 2-phase double-buffered
//     LDS pipeline in all GEMMs.

#define CDIM 512
#define NSP  4096
#define NB   4
#define PV_SPLITS 4

using bf16x8 = __attribute__((ext_vector_type(8))) __bf16;
using f32x4  = __attribute__((ext_vector_type(4))) float;
using u16x4  = __attribute__((ext_vector_type(4))) unsigned short;

__device__ __forceinline__ unsigned short f2bf(float f) {
  unsigned int u = __float_as_uint(f);
  u += 0x7fffu + ((u >> 16) & 1u);
  return (unsigned short)(u >> 16);
}

__device__ __forceinline__ void async_copy16(const unsigned short* g, unsigned short* l) {
  __builtin_amdgcn_global_load_lds(
      (const __attribute__((address_space(1))) void*)g,
      (__attribute__((address_space(3))) void*)l, 16, 0, 0);
}

// ---------------- GroupNorm stats: one block per (b, group) ----------------
__global__ __launch_bounds__(256) void gn_stats(const float* __restrict__ x,
                                                float* __restrict__ stats) {
  const size_t base = (size_t)blockIdx.x * 65536;  // 16 ch * 4096, contiguous
  const float4* p = (const float4*)(x + base);
  float s = 0.f, ss = 0.f;
  for (int i = threadIdx.x; i < 16384; i += 256) {
    float4 v = p[i];
    s  += v.x + v.y + v.z + v.w;
    ss += v.x*v.x + v.y*v.y + v.z*v.z + v.w*v.w;
  }
  for (int off = 32; off; off >>= 1) {
    s  += __shfl_xor(s, off);
    ss += __shfl_xor(ss, off);
  }
  __shared__ float rs[4], rss[4];
  const int w = threadIdx.x >> 6;
  if ((threadIdx.x & 63) == 0) { rs[w] = s; rss[w] = ss; }
  __syncthreads();
  if (threadIdx.x == 0) {
    float S  = rs[0] + rs[1] + rs[2] + rs[3];
    float SS = rss[0] + rss[1] + rss[2] + rss[3];
    float mean = S * (1.f / 65536.f);
    float var  = SS * (1.f / 65536.f) - mean * mean;
    stats[2 * blockIdx.x]     = mean;
    stats[2 * blockIdx.x + 1] = rsqrtf(var + 1e-6f);
  }
}

// ------------- normalize + transpose: x(B,C,N) f32 -> Hnt(B,N,C) bf16 -------
__global__ __launch_bounds__(256) void norm_transpose(
    const float* __restrict__ x, const float* __restrict__ stats,
    const float* __restrict__ gns, const float* __restrict__ gnb,
    unsigned short* __restrict__ hnt) {
  __shared__ float tile[64][65];
  const int b  = blockIdx.z;
  const int c0 = blockIdx.y * 64, n0 = blockIdx.x * 64;
  const int tx = threadIdx.x & 63, ty = threadIdx.x >> 6;
  for (int i = 0; i < 16; ++i) {
    int cl = ty * 16 + i;
    int c  = c0 + cl;
    int g  = c >> 4;
    float mean = stats[(b * 32 + g) * 2];
    float rstd = stats[(b * 32 + g) * 2 + 1];
    float v = x[((size_t)(b * CDIM + c)) * NSP + n0 + tx];
    tile[cl][tx] = (v - mean) * rstd * gns[c] + gnb[c];
  }
  __syncthreads();
  for (int i = 0; i < 16; ++i) {
    int nl = ty * 16 + i;
    hnt[((size_t)(b * NSP + n0 + nl)) * CDIM + c0 + tx] = f2bf(tile[tx][nl]);
  }
}

// ---------------- fp32 -> bf16 weight conversion ----------------
__global__ __launch_bounds__(256) void f32_to_bf16(const float* __restrict__ src,
                                                   unsigned short* __restrict__ dst) {
  int i = blockIdx.x * 256 + threadIdx.x;
  float4 v = ((const float4*)src)[i];
  u16x4 o = {f2bf(v.x), f2bf(v.y), f2bf(v.z), f2bf(v.w)};
  *(u16x4*)(dst + (size_t)i * 4) = o;
}

// ---------------- NT GEMM: D[M,N] = scale * A[M,K] @ Bt[N,K]^T ----------------
// BIAS_MODE: 0 none, 1 per-row (bias[m]), 2 per-col (bias[n])
// SPLITK: blockIdx.z = split index; k-range [z*kLen, (z+1)*kLen);
//         D (fp32) offset by z*M*N. Otherwise blockIdx.z = batch.
template <int BIAS_MODE, int OUT_BF16, int RESID, int SPLITK>
__global__ __launch_bounds__(256) void gemm_nt(
    const unsigned short* __restrict__ A, const unsigned short* __restrict__ Bt,
    void* __restrict__ Dv, const float* __restrict__ bias,
    const float* __restrict__ resid, int M, int N, int K, float scale,
    long sA, long sB, long sD, long sR, int kLen) {
  __shared__ unsigned short lsA[2][128 * 32];
  __shared__ unsigned short lsB[2][128 * 32];
  const int tid = threadIdx.x;
  const int w = tid >> 6, lane = tid & 63;
  const int wr = w >> 1, wc = w & 1;
  const int b = SPLITK ? 0 : blockIdx.z;
  const int bm0 = blockIdx.y * 128, bn0 = blockIdx.x * 128;
  const unsigned short* Ab = A + (size_t)b * sA;
  const unsigned short* Bb = Bt + (size_t)b * sB;
  const size_t dOff = SPLITK ? (size_t)blockIdx.z * (size_t)M * N
                             : (size_t)b * (size_t)sD;
  int kStart = SPLITK ? blockIdx.z * kLen : 0;
  int kEnd   = SPLITK ? kStart + kLen : K;

  f32x4 acc[4][4] = {};
  const int r0  = w * 16 + (lane >> 2);  // staging row within a 64-row half
  const int kof = (lane & 3) * 8;        // staging col (shorts)
  const int fr  = lane & 15, kf = (lane >> 4) * 8;

  // prologue: stage first tile into buffer 0
  for (int it = 0; it < 2; ++it) {
    int row = it * 64 + r0;
    async_copy16(Ab + (size_t)(bm0 + row) * K + kStart + kof, &lsA[0][row * 32 + kof]);
    async_copy16(Bb + (size_t)(bn0 + row) * K + kStart + kof, &lsB[0][row * 32 + kof]);
  }
  __syncthreads();

  int cur = 0;
  for (int k0 = kStart; k0 < kEnd; k0 += 32) {
    const int nk = k0 + 32;
    if (nk < kEnd) {  // prefetch next tile into the other buffer
      for (int it = 0; it < 2; ++it) {
        int row = it * 64 + r0;
        async_copy16(Ab + (size_t)(bm0 + row) * K + nk + kof, &lsA[cur ^ 1][row * 32 + kof]);
        async_copy16(Bb + (size_t)(bn0 + row) * K + nk + kof, &lsB[cur ^ 1][row * 32 + kof]);
      }
    }
    bf16x8 af[4], bff[4];
    for (int i = 0; i < 4; ++i) {
      af[i]  = *(const bf16x8*)(&lsA[cur][(wr * 64 + i * 16 + fr) * 32 + kf]);
      bff[i] = *(const bf16x8*)(&lsB[cur][(wc * 64 + i * 16 + fr) * 32 + kf]);
    }
    for (int i = 0; i < 4; ++i)
      for (int j = 0; j < 4; ++j)
        acc[i][j] = __builtin_amdgcn_mfma_f32_16x16x32_bf16(af[i], bff[j], acc[i][j], 0, 0, 0);
    __syncthreads();  // drains vmcnt(0): prefetch complete; reads of cur done
    cur ^= 1;
  }

  const int col_l = lane & 15, row_l = (lane >> 4) * 4;
  for (int i = 0; i < 4; ++i)
    for (int j = 0; j < 4; ++j) {
      int gr = bm0 + wr * 64 + i * 16 + row_l;
      int gc = bn0 + wc * 64 + j * 16 + col_l;
      for (int r = 0; r < 4; ++r) {
        float v = acc[i][j][r] * scale;
        if (BIAS_MODE == 1) v += bias[gr + r];
        if (BIAS_MODE == 2) v += bias[gc];
        if (RESID) v += resid[(size_t)b * sR + (size_t)(gr + r) * N + gc];
        if (OUT_BF16)
          ((unsigned short*)Dv)[dOff + (size_t)(gr + r) * N + gc] = f2bf(v);
        else
          ((float*)Dv)[dOff + (size_t)(gr + r) * N + gc] = v;
      }
    }
}

// ---------------- split-K reduce: sum fp32 partials -> bf16 ----------------
__global__ __launch_bounds__(256) void reduce_splitk(const float* __restrict__ part,
                                                     unsigned short* __restrict__ out) {
  const size_t total = (size_t)NSP * CDIM;  // 2M
  size_t i = ((size_t)blockIdx.x * 256 + threadIdx.x) * 4;
  float4 a = *(const float4*)(part + i);
  for (int s = 1; s < PV_SPLITS; ++s) {
    float4 p = *(const float4*)(part + s * total + i);
    a.x += p.x; a.y += p.y; a.z += p.z; a.w += p.w;
  }
  u16x4 o = {f2bf(a.x), f2bf(a.y), f2bf(a.z), f2bf(a.w)};
  *(u16x4*)(out + i) = o;
}

// ---------------- row softmax: S fp32 (4096 cols) -> P bf16 ----------------
__global__ __launch_bounds__(256) void softmax_rows(const float* __restrict__ S,
                                                    unsigned short* __restrict__ P) {
  const int row = blockIdx.x;
  const float4* s = (const float4*)(S + (size_t)row * NSP);
  const int t = threadIdx.x;
  float4 v[4];
  float m = -1e30f;
  for (int i = 0; i < 4; ++i) {
    v[i] = s[i * 256 + t];
    m = fmaxf(m, fmaxf(fmaxf(v[i].x, v[i].y), fmaxf(v[i].z, v[i].w)));
  }
  for (int off = 32; off; off >>= 1) m = fmaxf(m, __shfl_xor(m, off));
  __shared__ float red[8];
  const int w = t >> 6;
  if ((t & 63) == 0) red[w] = m;
  __syncthreads();
  m = fmaxf(fmaxf(red[0], red[1]), fmaxf(red[2], red[3]));
  float sum = 0.f;
  for (int i = 0; i < 4; ++i) {
    v[i].x = __expf(v[i].x - m);
    v[i].y = __expf(v[i].y - m);
    v[i].z = __expf(v[i].z - m);
    v[i].w = __expf(v[i].w - m);
    sum += v[i].x + v[i].y + v[i].z + v[i].w;
  }
  for (int off = 32; off; off >>= 1) sum += __shfl_xor(sum, off);
  if ((t & 63) == 0) red[4 + w] = sum;
  __syncthreads();
  float inv = 1.f / (red[4] + red[5] + red[6] + red[7]);
  for (int i = 0; i < 4; ++i) {
    u16x4 o = {f2bf(v[i].x * inv), f2bf(v[i].y * inv), f2bf(v[i].z * inv), f2bf(v[i].w * inv)};
    *(u16x4*)(P + (size_t)row * NSP + (size_t)(i * 256 + t) * 4) = o;
  }
}

extern "C" void kernel_launch(void* const* d_in, const int* in_sizes, int n_in,
                              void* d_out, int out_size, void* d_ws, size_t ws_size,
                              hipStream_t stream) {
  const float* hs  = (const float*)d_in[0];
  const float* gns = (const float*)d_in[1];
  const float* gnb = (const float*)d_in[2];
  const float* wq  = (const float*)d_in[3];
  const float* bq  = (const float*)d_in[4];
  const float* wk  = (const float*)d_in[5];
  const float* bk  = (const float*)d_in[6];
  const float* wv  = (const float*)d_in[7];
  const float* bv  = (const float*)d_in[8];
  const float* wp  = (const float*)d_in[9];
  const float* bp  = (const float*)d_in[10];

  char* p = (char*)d_ws;
  unsigned short* wqb = (unsigned short*)p; p += (size_t)CDIM * CDIM * 2;
  unsigned short* wkb = (unsigned short*)p; p += (size_t)CDIM * CDIM * 2;
  unsigned short* wvb = (unsigned short*)p; p += (size_t)CDIM * CDIM * 2;
  unsigned short* wpb = (unsigned short*)p; p += (size_t)CDIM * CDIM * 2;
  const size_t bn = (size_t)NSP * CDIM;         // 2M elements per batch
  unsigned short* hnt = (unsigned short*)p; p += NB * bn * 2;
  unsigned short* qt  = (unsigned short*)p; p += NB * bn * 2;
  unsigned short* kt  = (unsigned short*)p; p += NB * bn * 2;
  unsigned short* vcn = (unsigned short*)p; p += NB * bn * 2;
  unsigned short* ot  = (unsigned short*)p; p += NB * bn * 2;
  float* S = (float*)p;          p += (size_t)NSP * NSP * 4;  // also PV partials
  unsigned short* P = (unsigned short*)p; p += (size_t)NSP * NSP * 2;
  float* stats = (float*)p;      p += 256 * 4;

  f32_to_bf16<<<256, 256, 0, stream>>>(wq, wqb);
  f32_to_bf16<<<256, 256, 0, stream>>>(wk, wkb);
  f32_to_bf16<<<256, 256, 0, stream>>>(wv, wvb);
  f32_to_bf16<<<256, 256, 0, stream>>>(wp, wpb);
  gn_stats<<<128, 256, 0, stream>>>(hs, stats);
  norm_transpose<<<dim3(64, 8, 4), 256, 0, stream>>>(hs, stats, gns, gnb, hnt);

  const long sBN = (long)bn;
  // Qt[b] (4096x512) = Hnt[b](4096x512) @ Wq(512x512)^T + bq (per-col)
  gemm_nt<2, 1, 0, 0><<<dim3(4, 32, NB), 256, 0, stream>>>(
      hnt, wqb, qt, bq, nullptr, NSP, CDIM, CDIM, 1.f, sBN, 0, sBN, 0, 0);
  gemm_nt<2, 1, 0, 0><<<dim3(4, 32, NB), 256, 0, stream>>>(
      hnt, wkb, kt, bk, nullptr, NSP, CDIM, CDIM, 1.f, sBN, 0, sBN, 0, 0);
  // Vcn[b] (512x4096) = Wv(512x512) @ Hnt[b](4096x512)^T + bv (per-row)
  gemm_nt<1, 1, 0, 0><<<dim3(32, 4, NB), 256, 0, stream>>>(
      wvb, hnt, vcn, bv, nullptr, CDIM, NSP, CDIM, 1.f, 0, sBN, sBN, 0, 0);

  const float sc = 0.044194173824159216f;  // 512^-0.5
  for (int b = 0; b < NB; ++b) {
    // S (4096x4096 fp32) = Qt[b] @ Kt[b]^T * C^-0.5
    gemm_nt<0, 0, 0, 0><<<dim3(32, 32, 1), 256, 0, stream>>>(
        qt + (size_t)b * bn, kt + (size_t)b * bn, S, nullptr, nullptr,
        NSP, NSP, CDIM, sc, 0, 0, 0, 0, 0);
    softmax_rows<<<NSP, 256, 0, stream>>>(S, P);
    // PV split-K: partial[z] (4096x512 fp32) = P[:, z*1024:+1024] @ Vcn[b][:, same]^T
    // partials land in S's buffer (free after softmax)
    gemm_nt<0, 0, 0, 1><<<dim3(4, 32, PV_SPLITS), 256, 0, stream>>>(
        P, vcn + (size_t)b * bn, S, nullptr, nullptr,
        NSP, CDIM, NSP, 1.f, 0, 0, 0, 0, NSP / PV_SPLITS);
    reduce_splitk<<<2048, 256, 0, stream>>>(S, ot + (size_t)b * bn);
  }
  // out[b] (512x4096 fp32) = Wp @ Ot[b]^T + bp (per-row) + residual
  gemm_nt<1, 0, 1, 0><<<dim3(32, 4, NB), 256, 0, stream>>>(
      wpb, ot, (float*)d_out, bp, hs, CDIM, NSP, CDIM, 1.f, 0, sBN, sBN, sBN, 0);
}